// Round 7
// baseline (333.551 us; speedup 1.0000x reference)
//
#include <hip/hip_runtime.h>
#include <stdint.h>

// Problem constants (LTXSelfAttention: B=2, S=2048, D=2048, H=32, DH=64)
#define BD 2
#define SD 2048
#define DD 2048
#define HD 32
#define DH 64
#define MD (BD*SD)   // 4096 rows

typedef __attribute__((ext_vector_type(8))) short short8;
typedef __attribute__((ext_vector_type(8))) __bf16 bf16x8;
typedef __attribute__((ext_vector_type(4))) float f32x4;
typedef __attribute__((ext_vector_type(4))) unsigned int u32x4;
typedef unsigned short u16;
typedef unsigned int u32;

__device__ __forceinline__ u16 f2bf(float f) {
    u32 u = __float_as_uint(f);
    u32 r = (u + 0x7fffu + ((u >> 16) & 1u)) >> 16;   // RNE
    return (u16)r;
}
// packed f32x2 -> bf16x2 in one HW instr (D.lo = bf16(a), D.hi = bf16(b))
__device__ __forceinline__ u32 cvtpk(float a, float b) {
    u32 r;
    asm volatile("v_cvt_pk_bf16_f32 %0, %1, %2" : "=v"(r) : "v"(a), "v"(b));
    return r;
}
__device__ __forceinline__ float bf2f(u16 h) {
    return __uint_as_float(((u32)h) << 16);
}
__device__ __forceinline__ f32x4 mfma16(short8 a, short8 b, f32x4 c) {
    return __builtin_amdgcn_mfma_f32_16x16x32_bf16(
        __builtin_bit_cast(bf16x8, a), __builtin_bit_cast(bf16x8, b), c, 0, 0, 0);
}
// async global->LDS, 16B per lane (wave-uniform LDS base + lane*16, linear dest)
__device__ __forceinline__ void gload16(const void* g, void* l) {
    __builtin_amdgcn_global_load_lds(
        (const __attribute__((address_space(1))) u32*)g,
        (__attribute__((address_space(3))) u32*)l, 16, 0, 0);
}
#if __has_builtin(__builtin_amdgcn_exp2f)
__device__ __forceinline__ float exp2x(float x) { return __builtin_amdgcn_exp2f(x); }
#else
__device__ __forceinline__ float exp2x(float x) { return exp2f(x); }
#endif

// 0.125 (1/sqrt(DH)) * log2(e): scores arrive in log2-domain -> softmax uses exp2
#define QSCALE 0.18033688011112042f

// ---------------- fp32 -> bf16 convert ----------------
__global__ __launch_bounds__(256) void cvt_f32_bf16(const float* __restrict__ s,
                                                    u16* __restrict__ d, int n4) {
    int i = blockIdx.x * 256 + threadIdx.x;
    if (i >= n4) return;
    float4 v = reinterpret_cast<const float4*>(s)[i];
    reinterpret_cast<uint2*>(d)[i] = make_uint2(cvtpk(v.x, v.y), cvtpk(v.z, v.w));
}
__global__ __launch_bounds__(256) void cvt_w4(
    const float* __restrict__ s0, const float* __restrict__ s1,
    const float* __restrict__ s2, const float* __restrict__ s3,
    u16* __restrict__ d0, u16* __restrict__ d1, u16* __restrict__ d2, u16* __restrict__ d3,
    int n4) {
    int i = blockIdx.x * 256 + threadIdx.x;
    if (i >= n4) return;
    int z = blockIdx.y;
    const float* s = z == 0 ? s0 : z == 1 ? s1 : z == 2 ? s2 : s3;
    u16* d = z == 0 ? d0 : z == 1 ? d1 : z == 2 ? d2 : d3;
    float4 v = reinterpret_cast<const float4*>(s)[i];
    reinterpret_cast<uint2*>(d)[i] = make_uint2(cvtpk(v.x, v.y), cvtpk(v.z, v.w));
}

// ---------------- GEMM (QKV): phased m201-style template ----------------
// 256x128 tile, BK=32, 256 threads (4 waves as 2Mx2N, 128x64 per wave ->
// 12 b128 frag reads per 32 MFMA, A-frags reused across both N-phases).
// 2 LDS slots (48KB -> 2 blocks/CU co-resident, independent barriers stagger).
// Per K-step: STAGE(t+1), counted vmcnt(6) (never 0 in-loop), then two
// {reads; lgkmcnt(0); setprio; 16 MFMA; barrier} phases. Every read drained
// before the barrier preceding the overwriting STAGE -> WAR provably closed.
__global__ __launch_bounds__(256, 2) void gemm_qkv8(
    const u16* __restrict__ A,
    const u16* __restrict__ B0, const u16* __restrict__ B1, const u16* __restrict__ B2,
    const float* __restrict__ c0, const float* __restrict__ c1, const float* __restrict__ c2,
    u16* __restrict__ o0, u16* __restrict__ o1, u16* __restrict__ o2,
    int M, int N, int K)
{
    __shared__ __align__(16) u16 As[2][256 * 32];
    __shared__ __align__(16) u16 Bs[2][128 * 32];
    const int z = blockIdx.z;
    const u16* Bm = z == 0 ? B0 : (z == 1 ? B1 : B2);
    const float* bias = z == 0 ? c0 : (z == 1 ? c1 : c2);
    u16* outp = z == 0 ? o0 : (z == 1 ? o1 : o2);

    const int tid = threadIdx.x;
    const int m0 = blockIdx.y * 256;
    const int n0 = blockIdx.x * 128;
    const int lane = tid & 63, w = tid >> 6;
    const int wm = (w >> 1) * 128, wn = (w & 1) * 64;   // 2M x 2N wave grid
    const int lr = lane & 15, lg = lane >> 4;

    // staging: LDS pos (row, chunkpos) holds global chunk chunkpos^((row>>1)&3)
    const int srow = tid >> 2;                              // 0..63
    const int scol = ((tid & 3) ^ ((tid >> 3) & 3)) * 8;    // swizzled source col
    const u16* aS = A + (size_t)(m0 + srow) * K + scol;     // + 64p rows, p=0..3
    const u16* bS = Bm + (size_t)(n0 + srow) * K + scol;    // + 64p rows, p=0..1

#define STG(buf, kt) do {                                                       \
    gload16(aS + (size_t)(kt) * 32,                     &As[buf][tid * 8]);     \
    gload16(aS + (size_t)64 * K + (size_t)(kt) * 32,    &As[buf][tid * 8 + 2048]); \
    gload16(aS + (size_t)128 * K + (size_t)(kt) * 32,   &As[buf][tid * 8 + 4096]); \
    gload16(aS + (size_t)192 * K + (size_t)(kt) * 32,   &As[buf][tid * 8 + 6144]); \
    gload16(bS + (size_t)(kt) * 32,                     &Bs[buf][tid * 8]);     \
    gload16(bS + (size_t)64 * K + (size_t)(kt) * 32,    &Bs[buf][tid * 8 + 2048]); \
} while (0)

    f32x4 acc[8][4];
#pragma unroll
    for (int i = 0; i < 8; ++i)
#pragma unroll
        for (int j = 0; j < 4; ++j) acc[i][j] = (f32x4){0.f, 0.f, 0.f, 0.f};

    const int sa8 = (lg ^ ((lr >> 1) & 3)) * 8;   // swizzled chunk for frag reads

    STG(0, 0);

    const int KT = K / 32;   // 64
    for (int t = 0; t < KT; ++t) {
        const int cur = t & 1;
        if (t + 1 < KT) {
            STG(cur ^ 1, t + 1);
            asm volatile("s_waitcnt vmcnt(6)" ::: "memory");   // tile t landed; t+1 in flight
        } else {
            asm volatile("s_waitcnt vmcnt(0)" ::: "memory");   // tail drain
        }
        __builtin_amdgcn_s_barrier();
        __builtin_amdgcn_sched_barrier(0);

        const u16* aBase = &As[cur][(wm + lr) * 32 + sa8];
        const u16* bBase = &Bs[cur][(wn + lr) * 32 + sa8];
        short8 av[8], bv0, bv1, bv2, bv3;
#pragma unroll
        for (int i = 0; i < 8; ++i) av[i] = *(const short8*)(aBase + i * 512);
        bv0 = *(const short8*)(bBase);
        bv1 = *(const short8*)(bBase + 512);
        asm volatile("s_waitcnt lgkmcnt(0)" ::: "memory");
        __builtin_amdgcn_sched_barrier(0);
        __builtin_amdgcn_s_setprio(1);
#pragma unroll
        for (int i = 0; i < 8; ++i) {
            acc[i][0] = mfma16(av[i], bv0, acc[i][0]);
            acc[i][1] = mfma16(av[i], bv1, acc[i][1]);
        }
        __builtin_amdgcn_s_setprio(0);
        __builtin_amdgcn_s_barrier();
        __builtin_amdgcn_sched_barrier(0);

        bv2 = *(const short8*)(bBase + 1024);
        bv3 = *(const short8*)(bBase + 1536);
        asm volatile("s_waitcnt lgkmcnt(0)" ::: "memory");
        __builtin_amdgcn_sched_barrier(0);
        __builtin_amdgcn_s_setprio(1);
#pragma unroll
        for (int i = 0; i < 8; ++i) {
            acc[i][2] = mfma16(av[i], bv2, acc[i][2]);
            acc[i][3] = mfma16(av[i], bv3, acc[i][3]);
        }
        __builtin_amdgcn_s_setprio(0);
        __builtin_amdgcn_s_barrier();      // reads drained above -> next STG safe
        __builtin_amdgcn_sched_barrier(0);
    }
#undef STG

    // epilogue: C/D layout col = lane&15, row = (lane>>4)*4 + reg
#pragma unroll
    for (int j = 0; j < 4; ++j) {
        const int col = n0 + wn + j * 16 + lr;
        const float bj = bias[col];
#pragma unroll
        for (int i = 0; i < 8; ++i) {
            const int row = m0 + wm + i * 16 + lg * 4;
#pragma unroll
            for (int r = 0; r < 4; ++r)
                outp[(size_t)(row + r) * N + col] = f2bf(acc[i][j][r] + bj);
        }
    }
}

// ---------------- GEMM v4 (out-proj): known-good 3-buffer counted-vmcnt ----------
template<int OUTF32>
__global__ __launch_bounds__(512, 4) void gemm_nt4(
    const u16* __restrict__ A,
    const u16* __restrict__ B0, const u16* __restrict__ B1, const u16* __restrict__ B2,
    const float* __restrict__ c0, const float* __restrict__ c1, const float* __restrict__ c2,
    void* __restrict__ o0, void* __restrict__ o1, void* __restrict__ o2,
    int M, int N, int K)
{
    __shared__ __align__(16) u16 As[3][256 * 32];
    __shared__ __align__(16) u16 Bs[3][128 * 32];
    const int z = blockIdx.z;
    const u16* Bm = z == 0 ? B0 : (z == 1 ? B1 : B2);
    const float* bias = z == 0 ? c0 : (z == 1 ? c1 : c2);
    void* outp = z == 0 ? o0 : (z == 1 ? o1 : o2);

    const int tid = threadIdx.x;
    const int m0 = blockIdx.y * 256;
    const int n0 = blockIdx.x * 128;
    const int lane = tid & 63, w = tid >> 6;
    const int wm = (w >> 1) * 64, wn = (w & 1) * 64;
    const int lr = lane & 15, lg = lane >> 4;

    const int srow = tid >> 2;
    const int scol = ((tid & 3) ^ ((srow >> 1) & 3)) * 8;
    const u16* aS = A + (size_t)(m0 + srow) * K + scol;
    const u16* bS = Bm + (size_t)(n0 + srow) * K + scol;

#define STG(pa, pb, kt) do {                                                \
    gload16(aS + (size_t)(kt) * 32, (pa) + tid * 8);                        \
    gload16(aS + (size_t)128 * K + (size_t)(kt) * 32, (pa) + tid * 8 + 4096); \
    gload16(bS + (size_t)(kt) * 32, (pb) + tid * 8); } while (0)

    f32x4 acc[4][4];
#pragma unroll
    for (int i = 0; i < 4; ++i)
#pragma unroll
        for (int j = 0; j < 4; ++j) acc[i][j] = (f32x4){0.f, 0.f, 0.f, 0.f};

    const int sa8 = (lg ^ ((lr >> 1) & 3)) * 8;

    u16* a0 = As[0]; u16* a1 = As[1]; u16* a2 = As[2];
    u16* b0 = Bs[0]; u16* b1 = Bs[1]; u16* b2 = Bs[2];

    STG(a0, b0, 0);
    STG(a1, b1, 1);

    const int KT = K / 32;
    for (int t = 0; t < KT; ++t) {
        if (t < KT - 1) asm volatile("s_waitcnt vmcnt(3)" ::: "memory");
        else            asm volatile("s_waitcnt vmcnt(0)" ::: "memory");
        __builtin_amdgcn_s_barrier();
        __builtin_amdgcn_sched_barrier(0);

        const u16* aBase = a0 + (wm + lr) * 32 + sa8;
        const u16* bBase = b0 + (wn + lr) * 32 + sa8;
        short8 av[4], bv[4];
#pragma unroll
        for (int i = 0; i < 4; ++i) av[i] = *(const short8*)(aBase + i * 512);
#pragma unroll
        for (int j = 0; j < 4; ++j) bv[j] = *(const short8*)(bBase + j * 512);

        if (t + 2 < KT) STG(a2, b2, t + 2);

        __builtin_amdgcn_s_setprio(1);
#pragma unroll
        for (int i = 0; i < 4; ++i)
#pragma unroll
            for (int j = 0; j < 4; ++j) acc[i][j] = mfma16(av[i], bv[j], acc[i][j]);
        __builtin_amdgcn_s_setprio(0);

        u16* ta = a0; a0 = a1; a1 = a2; a2 = ta;
        u16* tb = b0; b0 = b1; b1 = b2; b2 = tb;
    }
#undef STG

#pragma unroll
    for (int j = 0; j < 4; ++j) {
        const int col = n0 + wn + j * 16 + lr;
        const float bj = bias[col];
#pragma unroll
        for (int i = 0; i < 4; ++i) {
            const int row = m0 + wm + i * 16 + lg * 4;
#pragma unroll
            for (int r = 0; r < 4; ++r) {
                float v = acc[i][j][r] + bj;
                if (OUTF32) ((float*)outp)[(size_t)(row + r) * N + col] = v;
                else        ((u16*)outp)[(size_t)(row + r) * N + col] = f2bf(v);
            }
        }
    }
}

// ---------------- fused RMSNorm + interleaved RoPE (q AND k per block) ------
__global__ __launch_bounds__(256) void rmsnorm_rope(
    u16* __restrict__ q, u16* __restrict__ k,
    const float* __restrict__ qw, const float* __restrict__ kw,
    const float* __restrict__ pc, const float* __restrict__ ps)
{
    const int row = blockIdx.x;           // 0..MD-1
    const int s = row & (SD - 1);
    const int off = threadIdx.x * 8;
    u16* qp = q + (size_t)row * DD + off;
    u16* kp = k + (size_t)row * DD + off;
    short8 qraw = *(const short8*)qp;
    short8 kraw = *(const short8*)kp;
    float vq[8], vk[8];
    float sq = 0.f, sk = 0.f;
#pragma unroll
    for (int j = 0; j < 8; ++j) {
        vq[j] = bf2f((u16)qraw[j]); sq += vq[j] * vq[j];
        vk[j] = bf2f((u16)kraw[j]); sk += vk[j] * vk[j];
    }
#pragma unroll
    for (int m = 1; m < 64; m <<= 1) { sq += __shfl_xor(sq, m, 64); sk += __shfl_xor(sk, m, 64); }
    __shared__ float redq[4], redk[4];
    const int w = threadIdx.x >> 6;
    if ((threadIdx.x & 63) == 0) { redq[w] = sq; redk[w] = sk; }
    __syncthreads();
    const float rq = rsqrtf((redq[0] + redq[1] + redq[2] + redq[3]) * (1.0f / DD) + 1e-6f);
    const float rk = rsqrtf((redk[0] + redk[1] + redk[2] + redk[3]) * (1.0f / DD) + 1e-6f);

    float wq[8], wk8[8], cv[8], sv[8];
    *(float4*)&wq[0]  = *(const float4*)(qw + off);
    *(float4*)&wq[4]  = *(const float4*)(qw + off + 4);
    *(float4*)&wk8[0] = *(const float4*)(kw + off);
    *(float4*)&wk8[4] = *(const float4*)(kw + off + 4);
    *(float4*)&cv[0] = *(const float4*)(pc + (size_t)s * DD + off);
    *(float4*)&cv[4] = *(const float4*)(pc + (size_t)s * DD + off + 4);
    *(float4*)&sv[0] = *(const float4*)(ps + (size_t)s * DD + off);
    *(float4*)&sv[4] = *(const float4*)(ps + (size_t)s * DD + off + 4);

    short8 qo, ko;
#pragma unroll
    for (int u = 0; u < 4; ++u) {
        float e  = vq[2 * u]     * rq * wq[2 * u];
        float od = vq[2 * u + 1] * rq * wq[2 * u + 1];
        qo[2 * u]     = (short)f2bf((e * cv[2 * u]      - od * sv[2 * u])     * QSCALE);
        qo[2 * u + 1] = (short)f2bf((od * cv[2 * u + 1] + e  * sv[2 * u + 1]) * QSCALE);
        e  = vk[2 * u]     * rk * wk8[2 * u];
        od = vk[2 * u + 1] * rk * wk8[2 * u + 1];
        ko[2 * u]     = (short)f2bf(e * cv[2 * u]      - od * sv[2 * u]);
        ko[2 * u + 1] = (short)f2bf(od * cv[2 * u + 1] + e  * sv[2 * u + 1]);
    }
    *(short8*)qp = qo;
    *(short8*)kp = ko;
}

// ---------------- V transpose: V[b,s,h*64+d] -> Vt[(b*32+h)*64+d][s] ----------------
__global__ __launch_bounds__(256) void transpose_v(
    const u16* __restrict__ v, u16* __restrict__ vt)
{
    __shared__ __align__(16) u16 t[64][80];
    const int bh = blockIdx.y;
    const int b = bh >> 5, h = bh & 31;
    const int s0 = blockIdx.x * 64;
    const int tid = threadIdx.x;
    const u16* src = v + (size_t)b * SD * DD + (size_t)h * DH;
#pragma unroll
    for (int i = 0; i < 2; ++i) {
        int c = tid + i * 256;
        int s = c >> 3, d8 = (c & 7) * 8;
        *(short8*)&t[s][d8] = *(const short8*)(src + (size_t)(s0 + s) * DD + d8);
    }
    __syncthreads();
    u16* dst = vt + (size_t)bh * DH * SD;
#pragma unroll
    for (int i = 0; i < 2; ++i) {
        int c = tid + i * 256;
        int d = c >> 3, s8 = (c & 7) * 8;
        short8 o;
#pragma unroll
        for (int j = 0; j < 8; ++j) o[j] = t[s8 + j][d];
        *(short8*)(dst + (size_t)d * SD + s0 + s8) = o;
    }
}

// ---------------- flash attention (swapped-QK^T, in-register P, swapped PV) ----------
__device__ __forceinline__ short8 swzread(const u16* base, int row, int colbyte) {
    return *(const short8*)((const char*)base + row * 128 + (colbyte ^ ((row & 7) << 4)));
}
__device__ __forceinline__ uint2 swz64(const u16* base, int row, int keyoff) {
    const int byteoff = keyoff * 2;
    const int addr = row * 128 + ((((byteoff >> 4) ^ (row & 7)) << 4) | (byteoff & 15));
    return *(const uint2*)((const char*)base + addr);
}

__global__ __launch_bounds__(512, 2) void attn_fwd(
    const u16* __restrict__ qb, const u16* __restrict__ kb,
    const u16* __restrict__ vt, u16* __restrict__ ob)
{
    __shared__ __align__(16) u16 Ksm[2][64 * 64];
    __shared__ __align__(16) u16 Vsm[2][64 * 64];
    const int bh = blockIdx.y;
    const int b = bh >> 5;
    const int q0 = blockIdx.x * 256;
    const int tid = threadIdx.x;
    const int w = tid >> 6, lane = tid & 63;
    const int lr = lane & 15, lg = lane >> 4;

    const size_t headoff = (size_t)b * SD * DD + (size_t)(bh & 31) * DH;
    const u16* kbase = kb + headoff;
    const u16* vtbase = vt + (size_t)bh * DH * SD;

    const u16* qrow = qb + headoff + (size_t)(q0 + w * 32 + lr) * DD + lg * 8;
    short8 qf[2][2];
    qf[0][0] = *(const short8*)qrow;
    qf[0][1] = *(const short8*)(qrow + 32);
    qf[1][0] = *(const short8*)(qrow + 16 * DD);
    qf[1][1] = *(const short8*)(qrow + 16 * DD + 32);

    f32x4 o[2][4];
#pragma unroll
    for (int s = 0; s < 2; ++s)
#pragma unroll
        for (int dt = 0; dt < 4; ++dt) o[s][dt] = (f32x4){0.f, 0.f, 0.f, 0.f};
    float m_[2] = {-1e30f, -1e30f};
    float l_[2] = {0.f, 0.f};

    const int rr = tid >> 3;
    const int cc = (tid & 7) ^ (rr & 7);

#define STAGE(buf, kv)                                                            \
    do {                                                                          \
        gload16(kbase + (size_t)((kv) + rr) * DD + cc * 8, &Ksm[buf][tid * 8]);   \
        gload16(vtbase + (size_t)rr * SD + (kv) + cc * 8, &Vsm[buf][tid * 8]);    \
    } while (0)

    STAGE(0, 0);
    asm volatile("s_waitcnt vmcnt(0)" ::: "memory");
    __syncthreads();

    for (int t = 0; t < SD / 64; ++t) {
        const int cur = t & 1;
        if (t + 1 < SD / 64) STAGE(cur ^ 1, (t + 1) * 64);

        const u16* Kc = Ksm[cur];
        const u16* Vc = Vsm[cur];

        f32x4 st[2][4];
        __builtin_amdgcn_s_setprio(1);
#pragma unroll
        for (int kt = 0; kt < 4; ++kt) {
            const int row = kt * 16 + lr;
            short8 kf0 = swzread(Kc, row, lg * 16);
            short8 kf1 = swzread(Kc, row, 64 + lg * 16);
            st[0][kt] = mfma16(kf1, qf[0][1], mfma16(kf0, qf[0][0], (f32x4){0.f, 0.f, 0.f, 0.f}));
            st[1][kt] = mfma16(kf1, qf[1][1], mfma16(kf0, qf[1][0], (f32x4){0.f, 0.f, 0.f, 0.f}));
        }
        __builtin_amdgcn_s_setprio(0);

        u32x4 pa[2][2];
#pragma unroll
        for (int sub = 0; sub < 2; ++sub) {
            float mx = st[sub][0][0];
#pragma unroll
            for (int kt = 0; kt < 4; ++kt)
#pragma unroll
                for (int r = 0; r < 4; ++r) mx = fmaxf(mx, st[sub][kt][r]);
            mx = fmaxf(mx, __shfl_xor(mx, 16, 64));
            mx = fmaxf(mx, __shfl_xor(mx, 32, 64));
            if (!__all(mx <= m_[sub] + 8.0f)) {
                const float mn = fmaxf(m_[sub], mx);
                const float fac = exp2x(m_[sub] - mn);
                m_[sub] = mn;
                l_[sub] *= fac;
#pragma unroll
                for (int dt = 0; dt < 4; ++dt)
#pragma unroll
                    for (int r = 0; r < 4; ++r) o[sub][dt][r] *= fac;
            }
            float p_[4][4];
            float rs = 0.f;
#pragma unroll
            for (int kt = 0; kt < 4; ++kt)
#pragma unroll
                for (int r = 0; r < 4; ++r) {
                    float pv = exp2x(st[sub][kt][r] - m_[sub]);
                    p_[kt][r] = pv;
                    rs += pv;
                }
            rs += __shfl_xor(rs, 16, 64);
            rs += __shfl_xor(rs, 32, 64);
            l_[sub] += rs;
#pragma unroll
            for (int ks = 0; ks < 2; ++ks) {
                u32x4 paw;
                paw[0] = cvtpk(p_[2 * ks][0], p_[2 * ks][1]);
                paw[1] = cvtpk(p_[2 * ks][2], p_[2 * ks][3]);
                paw[2] = cvtpk(p_[2 * ks + 1][0], p_[2 * ks + 1][1]);
                paw[3] = cvtpk(p_[2 * ks + 1][2], p_[2 * ks + 1][3]);
                pa[sub][ks] = paw;
            }
        }

        __builtin_amdgcn_s_setprio(1);
#pragma unroll
        for (int ks = 0; ks < 2; ++ks) {
#pragma unroll
            for (int dt = 0; dt < 4; ++dt) {
                const int d = dt * 16 + lr;
                uint2 vlo = swz64(Vc, d, ks * 32 + 4 * lg);
                uint2 vhi = swz64(Vc, d, ks * 32 + 16 + 4 * lg);
                u32x4 vw;
                vw[0] = vlo.x; vw[1] = vlo.y; vw[2] = vhi.x; vw[3] = vhi.y;
                short8 vf = __builtin_bit_cast(short8, vw);
                o[0][dt] = mfma16(vf, __builtin_bit_cast(short8, pa[0][ks]), o[0][dt]);
                o[1][dt] = mfma16(vf, __builtin_bit_cast(short8, pa[1][ks]), o[1][dt]);
            }
        }
        __builtin_amdgcn_s_setprio(0);

        asm volatile("s_waitcnt vmcnt(0)" ::: "memory");
        __syncthreads();
    }
#undef STAGE

#pragma unroll
    for (int sub = 0; sub < 2; ++sub) {
        const float li = 1.0f / l_[sub];
        const int srow = q0 + w * 32 + sub * 16 + lr;
#pragma unroll
        for (int dt = 0; dt < 4; ++dt) {
            u32 w0 = cvtpk(o[sub][dt][0] * li, o[sub][dt][1] * li);
            u32 w1 = cvtpk(o[sub][dt][2] * li, o[sub][dt][3] * li);
            *(uint2*)(ob + headoff + (size_t)srow * DD + dt * 16 + lg * 4) = make_uint2(w0, w1);
        }
    }
}

// ---------------- launch ----------------
extern "C" void kernel_launch(void* const* d_in, const int* in_sizes, int n_in,
                              void* d_out, int out_size, void* d_ws, size_t ws_size,
                              hipStream_t stream)
{
    (void)in_sizes; (void)n_in; (void)out_size; (void)ws_size;
    const float* x  = (const float*)d_in[0];
    const float* pc = (const float*)d_in[1];
    const float* ps = (const float*)d_in[2];
    const float* Wq = (const float*)d_in[3];
    const float* bq = (const float*)d_in[4];
    const float* Wk = (const float*)d_in[5];
    const float* bk = (const float*)d_in[6];
    const float* Wv = (const float*)d_in[7];
    const float* bv = (const float*)d_in[8];
    const float* qw = (const float*)d_in[9];
    const float* kw = (const float*)d_in[10];
    const float* Wo = (const float*)d_in[11];
    const float* bo = (const float*)d_in[12];
    float* out = (float*)d_out;

    const size_t MDsz = (size_t)MD * DD;
    const size_t DDsz = (size_t)DD * DD;
    u16* xb   = (u16*)d_ws;
    u16* wqb  = xb  + MDsz;
    u16* wkb  = wqb + DDsz;
    u16* wvb  = wkb + DDsz;
    u16* wob  = wvb + DDsz;
    u16* qbuf = wob + DDsz;
    u16* kbuf = qbuf + MDsz;
    u16* vbuf = kbuf + MDsz;
    u16* aob  = xb;            // attn output aliases xb (dead after QKV GEMM)
    u16* vtb  = wqb;           // V^T aliases wqb+wkb (dead after QKV GEMM)

    const int n4m = (int)(MDsz / 4), n4d = (int)(DDsz / 4);
    cvt_f32_bf16<<<dim3((n4m + 255) / 256), 256, 0, stream>>>(x, xb, n4m);
    cvt_w4<<<dim3((n4d + 255) / 256, 4), 256, 0, stream>>>(
        Wq, Wk, Wv, Wo, wqb, wkb, wvb, wob, n4d);

    // QKV projections fused over grid.z; 256x128 tiles -> (16,16,3) = 768 blocks
    gemm_qkv8<<<dim3(DD / 128, MD / 256, 3), 256, 0, stream>>>(
        xb, wqb, wkb, wvb, bq, bk, bv,
        qbuf, kbuf, vbuf, MD, DD, DD);

    rmsnorm_rope<<<dim3(MD), 256, 0, stream>>>(qbuf, kbuf, qw, kw, pc, ps);
    transpose_v<<<dim3(SD / 64, BD * HD), 256, 0, stream>>>(vbuf, vtb);

    attn_fwd<<<dim3(SD / 256, BD * HD), 512, 0, stream>>>(qbuf, kbuf, vtb, aob);

    gemm_nt4<1><<<dim3(DD / 128, MD / 256, 1), 512, 0, stream>>>(
        aob, wob, wob, wob, bo, bo, bo,
        (void*)out, (void*)out, (void*)out, MD, DD, DD);
}

// Round 9
// 279.730 us; speedup vs baseline: 1.1924x; 1.1924x over previous
//
#include <hip/hip_runtime.h>
#include <stdint.h>

// Problem constants (LTXSelfAttention: B=2, S=2048, D=2048, H=32, DH=64)
#define BD 2
#define SD 2048
#define DD 2048
#define HD 32
#define DH 64
#define MD (BD*SD)   // 4096 rows

typedef __attribute__((ext_vector_type(8))) short short8;
typedef __attribute__((ext_vector_type(8))) __bf16 bf16x8;
typedef __attribute__((ext_vector_type(4))) float f32x4;
typedef __attribute__((ext_vector_type(4))) unsigned int u32x4;
typedef unsigned short u16;
typedef unsigned int u32;

__device__ __forceinline__ u16 f2bf(float f) {
    u32 u = __float_as_uint(f);
    u32 r = (u + 0x7fffu + ((u >> 16) & 1u)) >> 16;   // RNE
    return (u16)r;
}
// packed f32x2 -> bf16x2 in one HW instr (D.lo = bf16(a), D.hi = bf16(b))
__device__ __forceinline__ u32 cvtpk(float a, float b) {
    u32 r;
    asm volatile("v_cvt_pk_bf16_f32 %0, %1, %2" : "=v"(r) : "v"(a), "v"(b));
    return r;
}
__device__ __forceinline__ float bf2f(u16 h) {
    return __uint_as_float(((u32)h) << 16);
}
__device__ __forceinline__ f32x4 mfma16(short8 a, short8 b, f32x4 c) {
    return __builtin_amdgcn_mfma_f32_16x16x32_bf16(
        __builtin_bit_cast(bf16x8, a), __builtin_bit_cast(bf16x8, b), c, 0, 0, 0);
}
// async global->LDS, 16B per lane (wave-uniform LDS base + lane*16, linear dest)
__device__ __forceinline__ void gload16(const void* g, void* l) {
    __builtin_amdgcn_global_load_lds(
        (const __attribute__((address_space(1))) u32*)g,
        (__attribute__((address_space(3))) u32*)l, 16, 0, 0);
}
#if __has_builtin(__builtin_amdgcn_exp2f)
__device__ __forceinline__ float exp2x(float x) { return __builtin_amdgcn_exp2f(x); }
#else
__device__ __forceinline__ float exp2x(float x) { return exp2f(x); }
#endif

// 0.125 (1/sqrt(DH)) * log2(e): scores arrive in log2-domain -> softmax uses exp2
#define QSCALE 0.18033688011112042f

// ---------------- fp32 -> bf16 convert: 4 weights + x (2 chunks) in one launch ----
__global__ __launch_bounds__(256) void cvt_all(
    const float* __restrict__ x,
    const float* __restrict__ s0, const float* __restrict__ s1,
    const float* __restrict__ s2, const float* __restrict__ s3,
    u16* __restrict__ xd,
    u16* __restrict__ d0, u16* __restrict__ d1, u16* __restrict__ d2, u16* __restrict__ d3,
    int n4d) {
    int i = blockIdx.x * 256 + threadIdx.x;
    if (i >= n4d) return;
    int z = blockIdx.y;
    const float* s;
    u16* d;
    if (z < 4) {
        s = z == 0 ? s0 : z == 1 ? s1 : z == 2 ? s2 : s3;
        d = z == 0 ? d0 : z == 1 ? d1 : z == 2 ? d2 : d3;
    } else {
        const size_t off = (size_t)(z - 4) * n4d;   // in float4 chunks
        s = x + off * 4;                            // 4 floats per chunk
        d = xd + off * 4;                           // 4 u16 per chunk (BUG FIX: was *8)
    }
    float4 v = reinterpret_cast<const float4*>(s)[i];
    reinterpret_cast<uint2*>(d)[i] = make_uint2(cvtpk(v.x, v.y), cvtpk(v.z, v.w));
}

// ---------------- GEMM v4: C[M,N] = A[M,K]*B[N,K]^T + bias ----------------
// 256x128 tile, BK=32, 512 threads (8 waves as 4Mx2N, 64x64 per wave).
// THREE rotating LDS buffers (72KB, 2 blocks/CU), 2-deep prefetch, ONE barrier +
// counted vmcnt(3) per K-step. XOR-swizzle keeps ds_read_b128 conflict-free.
// OUTF32==0 && z==2: V output written TRANSPOSED into vt[(b*32+h)*64+d][s]
// (fuses the old transpose_v kernel into the epilogue).
template<int OUTF32>
__global__ __launch_bounds__(512, 4) void gemm_nt4(
    const u16* __restrict__ A,
    const u16* __restrict__ B0, const u16* __restrict__ B1, const u16* __restrict__ B2,
    const float* __restrict__ c0, const float* __restrict__ c1, const float* __restrict__ c2,
    void* __restrict__ o0, void* __restrict__ o1, void* __restrict__ o2,
    int M, int N, int K)
{
    __shared__ __align__(16) u16 As[3][256 * 32];
    __shared__ __align__(16) u16 Bs[3][128 * 32];
    const int z = blockIdx.z;
    const u16* Bm = z == 0 ? B0 : (z == 1 ? B1 : B2);
    const float* bias = z == 0 ? c0 : (z == 1 ? c1 : c2);
    void* outp = z == 0 ? o0 : (z == 1 ? o1 : o2);

    const int tid = threadIdx.x;
    const int m0 = blockIdx.y * 256;
    const int n0 = blockIdx.x * 128;
    const int lane = tid & 63, w = tid >> 6;
    const int wm = (w >> 1) * 64, wn = (w & 1) * 64;   // 4M x 2N wave grid
    const int lr = lane & 15, lg = lane >> 4;

    const int srow = tid >> 2;
    const int scol = ((tid & 3) ^ ((srow >> 1) & 3)) * 8;
    const u16* aS = A + (size_t)(m0 + srow) * K + scol;
    const u16* bS = Bm + (size_t)(n0 + srow) * K + scol;

#define STG(pa, pb, kt) do {                                                \
    gload16(aS + (size_t)(kt) * 32, (pa) + tid * 8);                        \
    gload16(aS + (size_t)128 * K + (size_t)(kt) * 32, (pa) + tid * 8 + 4096); \
    gload16(bS + (size_t)(kt) * 32, (pb) + tid * 8); } while (0)

    f32x4 acc[4][4];
#pragma unroll
    for (int i = 0; i < 4; ++i)
#pragma unroll
        for (int j = 0; j < 4; ++j) acc[i][j] = (f32x4){0.f, 0.f, 0.f, 0.f};

    const int sa8 = (lg ^ ((lr >> 1) & 3)) * 8;

    u16* a0 = As[0]; u16* a1 = As[1]; u16* a2 = As[2];
    u16* b0 = Bs[0]; u16* b1 = Bs[1]; u16* b2 = Bs[2];

    STG(a0, b0, 0);
    STG(a1, b1, 1);

    const int KT = K / 32;
    for (int t = 0; t < KT; ++t) {
        if (t < KT - 1) asm volatile("s_waitcnt vmcnt(3)" ::: "memory");
        else            asm volatile("s_waitcnt vmcnt(0)" ::: "memory");
        __builtin_amdgcn_s_barrier();
        __builtin_amdgcn_sched_barrier(0);

        const u16* aBase = a0 + (wm + lr) * 32 + sa8;
        const u16* bBase = b0 + (wn + lr) * 32 + sa8;
        short8 av[4], bv[4];
#pragma unroll
        for (int i = 0; i < 4; ++i) av[i] = *(const short8*)(aBase + i * 512);
#pragma unroll
        for (int j = 0; j < 4; ++j) bv[j] = *(const short8*)(bBase + j * 512);

        if (t + 2 < KT) STG(a2, b2, t + 2);

        __builtin_amdgcn_s_setprio(1);
#pragma unroll
        for (int i = 0; i < 4; ++i)
#pragma unroll
            for (int j = 0; j < 4; ++j) acc[i][j] = mfma16(av[i], bv[j], acc[i][j]);
        __builtin_amdgcn_s_setprio(0);

        u16* ta = a0; a0 = a1; a1 = a2; a2 = ta;
        u16* tb = b0; b0 = b1; b1 = b2; b2 = tb;
    }
#undef STG

    // epilogue: C/D layout col = lane&15, row = (lane>>4)*4 + reg
    if (OUTF32 == 0 && z == 2) {
        // V: write transposed -> vt[(b*32 + col/64)*64 + col%64][s]
        const int bidx = m0 >> 11;              // batch (blocks never straddle 2048)
        const int s0 = (m0 & 2047) + wm;        // seq offset of this wave's rows
#pragma unroll
        for (int j = 0; j < 4; ++j) {
            const int col = n0 + wn + j * 16 + lr;
            const float bj = bias[col];
            u16* vcol = (u16*)outp +
                ((size_t)(bidx * 32 + (col >> 6)) * 64 + (col & 63)) * SD + s0;
#pragma unroll
            for (int i = 0; i < 4; ++i)
#pragma unroll
                for (int r = 0; r < 4; ++r)
                    vcol[i * 16 + lg * 4 + r] = f2bf(acc[i][j][r] + bj);
        }
    } else {
#pragma unroll
        for (int j = 0; j < 4; ++j) {
            const int col = n0 + wn + j * 16 + lr;
            const float bj = bias[col];
#pragma unroll
            for (int i = 0; i < 4; ++i) {
                const int row = m0 + wm + i * 16 + lg * 4;
#pragma unroll
                for (int r = 0; r < 4; ++r) {
                    float v = acc[i][j][r] + bj;
                    if (OUTF32) ((float*)outp)[(size_t)(row + r) * N + col] = v;
                    else        ((u16*)outp)[(size_t)(row + r) * N + col] = f2bf(v);
                }
            }
        }
    }
}

// ---------------- fused RMSNorm + interleaved RoPE (q AND k per block) ------
__global__ __launch_bounds__(256) void rmsnorm_rope(
    u16* __restrict__ q, u16* __restrict__ k,
    const float* __restrict__ qw, const float* __restrict__ kw,
    const float* __restrict__ pc, const float* __restrict__ ps)
{
    const int row = blockIdx.x;           // 0..MD-1
    const int s = row & (SD - 1);
    const int off = threadIdx.x * 8;
    u16* qp = q + (size_t)row * DD + off;
    u16* kp = k + (size_t)row * DD + off;
    short8 qraw = *(const short8*)qp;
    short8 kraw = *(const short8*)kp;
    float vq[8], vk[8];
    float sq = 0.f, sk = 0.f;
#pragma unroll
    for (int j = 0; j < 8; ++j) {
        vq[j] = bf2f((u16)qraw[j]); sq += vq[j] * vq[j];
        vk[j] = bf2f((u16)kraw[j]); sk += vk[j] * vk[j];
    }
#pragma unroll
    for (int m = 1; m < 64; m <<= 1) { sq += __shfl_xor(sq, m, 64); sk += __shfl_xor(sk, m, 64); }
    __shared__ float redq[4], redk[4];
    const int w = threadIdx.x >> 6;
    if ((threadIdx.x & 63) == 0) { redq[w] = sq; redk[w] = sk; }
    __syncthreads();
    const float rq = rsqrtf((redq[0] + redq[1] + redq[2] + redq[3]) * (1.0f / DD) + 1e-6f);
    const float rk = rsqrtf((redk[0] + redk[1] + redk[2] + redk[3]) * (1.0f / DD) + 1e-6f);

    float wq[8], wk8[8], cv[8], sv[8];
    *(float4*)&wq[0]  = *(const float4*)(qw + off);
    *(float4*)&wq[4]  = *(const float4*)(qw + off + 4);
    *(float4*)&wk8[0] = *(const float4*)(kw + off);
    *(float4*)&wk8[4] = *(const float4*)(kw + off + 4);
    *(float4*)&cv[0] = *(const float4*)(pc + (size_t)s * DD + off);
    *(float4*)&cv[4] = *(const float4*)(pc + (size_t)s * DD + off + 4);
    *(float4*)&sv[0] = *(const float4*)(ps + (size_t)s * DD + off);
    *(float4*)&sv[4] = *(const float4*)(ps + (size_t)s * DD + off + 4);

    short8 qo, ko;
#pragma unroll
    for (int u = 0; u < 4; ++u) {
        float e  = vq[2 * u]     * rq * wq[2 * u];
        float od = vq[2 * u + 1] * rq * wq[2 * u + 1];
        qo[2 * u]     = (short)f2bf((e * cv[2 * u]      - od * sv[2 * u])     * QSCALE);
        qo[2 * u + 1] = (short)f2bf((od * cv[2 * u + 1] + e  * sv[2 * u + 1]) * QSCALE);
        e  = vk[2 * u]     * rk * wk8[2 * u];
        od = vk[2 * u + 1] * rk * wk8[2 * u + 1];
        ko[2 * u]     = (short)f2bf(e * cv[2 * u]      - od * sv[2 * u]);
        ko[2 * u + 1] = (short)f2bf(od * cv[2 * u + 1] + e  * sv[2 * u + 1]);
    }
    *(short8*)qp = qo;
    *(short8*)kp = ko;
}

// ---------------- flash attention (swapped-QK^T, in-register P, swapped PV) ----------
// block = 512 thr (8 waves), grid = (S/256, B*H). Wave: 32 q-rows (2 sub-tiles of 16).
// K,Vt in XOR-swizzled LDS, THREE rotating slots, counted vmcnt(2) (never a full
// drain in-loop): STAGE(t+2) issued right after the top barrier; tile t+1 stays
// in flight through the whole compute phase. WAR safe: waves past barrier t have
// executed t-1's MFMAs => lgkm-drained those reads; STAGE touches slot (t-1)%3 only.
__device__ __forceinline__ short8 swzread(const u16* base, int row, int colbyte) {
    return *(const short8*)((const char*)base + row * 128 + (colbyte ^ ((row & 7) << 4)));
}
__device__ __forceinline__ uint2 swz64(const u16* base, int row, int keyoff) {
    const int byteoff = keyoff * 2;
    const int addr = row * 128 + ((((byteoff >> 4) ^ (row & 7)) << 4) | (byteoff & 15));
    return *(const uint2*)((const char*)base + addr);
}

__global__ __launch_bounds__(512, 2) void attn_fwd(
    const u16* __restrict__ qb, const u16* __restrict__ kb,
    const u16* __restrict__ vt, u16* __restrict__ ob)
{
    __shared__ __align__(16) u16 Ksm[3][64 * 64];
    __shared__ __align__(16) u16 Vsm[3][64 * 64];
    const int bh = blockIdx.y;
    const int b = bh >> 5;
    const int q0 = blockIdx.x * 256;
    const int tid = threadIdx.x;
    const int w = tid >> 6, lane = tid & 63;
    const int lr = lane & 15, lg = lane >> 4;

    const size_t headoff = (size_t)b * SD * DD + (size_t)(bh & 31) * DH;
    const u16* kbase = kb + headoff;
    const u16* vtbase = vt + (size_t)bh * DH * SD;

    // Q fragments (MFMA B-operand: col=q=lane&15, k=(lane>>4)*8+j)
    const u16* qrow = qb + headoff + (size_t)(q0 + w * 32 + lr) * DD + lg * 8;
    short8 qf[2][2];
    qf[0][0] = *(const short8*)qrow;
    qf[0][1] = *(const short8*)(qrow + 32);
    qf[1][0] = *(const short8*)(qrow + 16 * DD);
    qf[1][1] = *(const short8*)(qrow + 16 * DD + 32);

    f32x4 o[2][4];
#pragma unroll
    for (int s = 0; s < 2; ++s)
#pragma unroll
        for (int dt = 0; dt < 4; ++dt) o[s][dt] = (f32x4){0.f, 0.f, 0.f, 0.f};
    float m_[2] = {-1e30f, -1e30f};
    float l_[2] = {0.f, 0.f};

    const int rr = tid >> 3;
    const int cc = (tid & 7) ^ (rr & 7);

#define STAGE(kp, vp, kv)                                                         \
    do {                                                                          \
        gload16(kbase + (size_t)((kv) + rr) * DD + cc * 8, (kp) + tid * 8);       \
        gload16(vtbase + (size_t)rr * SD + (kv) + cc * 8, (vp) + tid * 8);        \
    } while (0)

    u16 *k0 = Ksm[0], *k1 = Ksm[1], *k2 = Ksm[2];
    u16 *v0 = Vsm[0], *v1 = Vsm[1], *v2 = Vsm[2];

    STAGE(k0, v0, 0);
    STAGE(k1, v1, 64);

    const int NT = SD / 64;
    for (int t = 0; t < NT; ++t) {
        if (t < NT - 1) asm volatile("s_waitcnt vmcnt(2)" ::: "memory");
        else            asm volatile("s_waitcnt vmcnt(0)" ::: "memory");
        __builtin_amdgcn_s_barrier();
        __builtin_amdgcn_sched_barrier(0);
        if (t + 2 < NT) STAGE(k2, v2, (t + 2) * 64);

        const u16* Kc = k0;
        const u16* Vc = v0;

        // swapped scores: st[sub][kt][r] = S[key=16kt+4lg+r][q=q0+w*32+sub*16+lr]
        f32x4 st[2][4];
        __builtin_amdgcn_s_setprio(1);
#pragma unroll
        for (int kt = 0; kt < 4; ++kt) {
            const int row = kt * 16 + lr;
            short8 kf0 = swzread(Kc, row, lg * 16);
            short8 kf1 = swzread(Kc, row, 64 + lg * 16);
            st[0][kt] = mfma16(kf1, qf[0][1], mfma16(kf0, qf[0][0], (f32x4){0.f, 0.f, 0.f, 0.f}));
            st[1][kt] = mfma16(kf1, qf[1][1], mfma16(kf0, qf[1][0], (f32x4){0.f, 0.f, 0.f, 0.f}));
        }
        __builtin_amdgcn_s_setprio(0);

        // softmax (log2 domain): per-lane over 16 keys + 2 shfl_xor over lane groups
        u32x4 pa[2][2];
#pragma unroll
        for (int sub = 0; sub < 2; ++sub) {
            float mx = st[sub][0][0];
#pragma unroll
            for (int kt = 0; kt < 4; ++kt)
#pragma unroll
                for (int r = 0; r < 4; ++r) mx = fmaxf(mx, st[sub][kt][r]);
            mx = fmaxf(mx, __shfl_xor(mx, 16, 64));
            mx = fmaxf(mx, __shfl_xor(mx, 32, 64));
            // defer-max (T13): only rescale when some q's max grew past threshold
            if (!__all(mx <= m_[sub] + 8.0f)) {
                const float mn = fmaxf(m_[sub], mx);
                const float fac = exp2x(m_[sub] - mn);
                m_[sub] = mn;
                l_[sub] *= fac;
#pragma unroll
                for (int dt = 0; dt < 4; ++dt)
#pragma unroll
                    for (int r = 0; r < 4; ++r) o[sub][dt][r] *= fac;
            }
            float p_[4][4];
            float rs = 0.f;
#pragma unroll
            for (int kt = 0; kt < 4; ++kt)
#pragma unroll
                for (int r = 0; r < 4; ++r) {
                    float pv = exp2x(st[sub][kt][r] - m_[sub]);
                    p_[kt][r] = pv;
                    rs += pv;
                }
            rs += __shfl_xor(rs, 16, 64);
            rs += __shfl_xor(rs, 32, 64);
            l_[sub] += rs;
            // pack own keys into B-operand frags, key order pi = ks*32+(j>>2)*16+lg*4+(j&3)
#pragma unroll
            for (int ks = 0; ks < 2; ++ks) {
                u32x4 paw;
                paw[0] = cvtpk(p_[2 * ks][0], p_[2 * ks][1]);
                paw[1] = cvtpk(p_[2 * ks][2], p_[2 * ks][3]);
                paw[2] = cvtpk(p_[2 * ks + 1][0], p_[2 * ks + 1][1]);
                paw[3] = cvtpk(p_[2 * ks + 1][2], p_[2 * ks + 1][3]);
                pa[sub][ks] = paw;
            }
        }

        // PV swapped: o = mfma(V, P). A=V^T[d][key pi], B=P[key pi][q]
        __builtin_amdgcn_s_setprio(1);
#pragma unroll
        for (int ks = 0; ks < 2; ++ks) {
#pragma unroll
            for (int dt = 0; dt < 4; ++dt) {
                const int d = dt * 16 + lr;
                uint2 vlo = swz64(Vc, d, ks * 32 + 4 * lg);
                uint2 vhi = swz64(Vc, d, ks * 32 + 16 + 4 * lg);
                u32x4 vw;
                vw[0] = vlo.x; vw[1] = vlo.y; vw[2] = vhi.x; vw[3] = vhi.y;
                short8 vf = __builtin_bit_cast(short8, vw);
                o[0][dt] = mfma16(vf, __builtin_bit_cast(short8, pa[0][ks]), o[0][dt]);
                o[1][dt] = mfma16(vf, __builtin_bit_cast(short8, pa[1][ks]), o[1][dt]);
            }
        }
        __builtin_amdgcn_s_setprio(0);

        // rotate slots
        u16* tk = k0; k0 = k1; k1 = k2; k2 = tk;
        u16* tv = v0; v0 = v1; v1 = v2; v2 = tv;
    }
#undef STAGE

    // epilogue: o[sub][dt][r] = O[q=q0+w*32+sub*16+lr][d=dt*16+lg*4+r] — per-lane
#pragma unroll
    for (int sub = 0; sub < 2; ++sub) {
        const float li = 1.0f / l_[sub];
        const int srow = q0 + w * 32 + sub * 16 + lr;
#pragma unroll
        for (int dt = 0; dt < 4; ++dt) {
            u32 w0 = cvtpk(o[sub][dt][0] * li, o[sub][dt][1] * li);
            u32 w1 = cvtpk(o[sub][dt][2] * li, o[sub][dt][3] * li);
            *(uint2*)(ob + headoff + (size_t)srow * DD + dt * 16 + lg * 4) = make_uint2(w0, w1);
        }
    }
}

// ---------------- launch ----------------
extern "C" void kernel_launch(void* const* d_in, const int* in_sizes, int n_in,
                              void* d_out, int out_size, void* d_ws, size_t ws_size,
                              hipStream_t stream)
{
    (void)in_sizes; (void)n_in; (void)out_size; (void)ws_size;
    const float* x  = (const float*)d_in[0];
    const float* pc = (const float*)d_in[1];
    const float* ps = (const float*)d_in[2];
    const float* Wq = (const float*)d_in[3];
    const float* bq = (const float*)d_in[4];
    const float* Wk = (const float*)d_in[5];
    const float* bk = (const float*)d_in[6];
    const float* Wv = (const float*)d_in[7];
    const float* bv = (const float*)d_in[8];
    const float* qw = (const float*)d_in[9];
    const float* kw = (const float*)d_in[10];
    const float* Wo = (const float*)d_in[11];
    const float* bo = (const float*)d_in[12];
    float* out = (float*)d_out;

    const size_t MDsz = (size_t)MD * DD;
    const size_t DDsz = (size_t)DD * DD;
    u16* xb   = (u16*)d_ws;
    u16* wqb  = xb  + MDsz;
    u16* wkb  = wqb + DDsz;
    u16* wvb  = wkb + DDsz;
    u16* wob  = wvb + DDsz;
    u16* qbuf = wob + DDsz;
    u16* kbuf = qbuf + MDsz;
    u16* vtb  = kbuf + MDsz;   // V^T written directly by the V-GEMM epilogue
    u16* aob  = xb;            // attn output aliases xb (dead after QKV GEMM)

    const int n4d = (int)(DDsz / 4);
    // y = 0..3: Wq,Wk,Wv,Wo; y = 4,5: x halves
    cvt_all<<<dim3((n4d + 255) / 256, 6), 256, 0, stream>>>(
        x, Wq, Wk, Wv, Wo, xb, wqb, wkb, wvb, wob, n4d);

    // QKV projections fused over grid.z; z==2 writes V transposed into vtb
    gemm_nt4<0><<<dim3(DD / 128, MD / 256, 3), 512, 0, stream>>>(
        xb, wqb, wkb, wvb, bq, bk, bv,
        (void*)qbuf, (void*)kbuf, (void*)vtb, MD, DD, DD);

    rmsnorm_rope<<<dim3(MD), 256, 0, stream>>>(qbuf, kbuf, qw, kw, pc, ps);

    attn_fwd<<<dim3(SD / 256, BD * HD), 512, 0, stream>>>(qbuf, kbuf, vtb, aob);

    gemm_nt4<1><<<dim3(DD / 128, MD / 256, 1), 512, 0, stream>>>(
        aob, wob, wob, wob, bo, bo, bo,
        (void*)out, (void*)out, (void*)out, MD, DD, DD);
}